// Round 5
// baseline (590.266 us; speedup 1.0000x reference)
//
#include <hip/hip_runtime.h>
#include <hip/hip_fp16.h>
#include <math.h>

#define HH 512
#define WW 512
#define NIMG 8
#define NPIX (NIMG * HH * WW)          // 2,097,152
#define GAMMA_FLOW 0.001f
#define GAMMA_MASK 0.0005f
#define INV_TOTAL (1.0f / (float)(NPIX * 3))

__device__ __forceinline__ float tanh_fast(float x)
{
    float e = __expf(2.0f * x);
    return 1.0f - 2.0f / (e + 1.0f);
}

// ================= K0: frames fp32 NHWC(6) -> two planar fp16 (padded 4/px) ==
__global__ __launch_bounds__(256) void cvt_kernel(
    const float* __restrict__ frames,
    __half* __restrict__ f0h, __half* __restrict__ f1h)
{
    int t = blockIdx.x * 256 + threadIdx.x;            // one pixel
    const float2* fp = reinterpret_cast<const float2*>(frames + (size_t)t * 6);
    float2 v0 = fp[0], v1 = fp[1], v2 = fp[2];
    __half2 a = __floats2half2_rn(v0.x, v0.y);         // f0 ch0,ch1
    __half2 b = __floats2half2_rn(v1.x, 0.0f);         // f0 ch2, pad
    __half2 c = __floats2half2_rn(v1.y, v2.x);         // f1 ch0,ch1
    __half2 d = __floats2half2_rn(v2.y, 0.0f);         // f1 ch2, pad
    __half2* p0 = reinterpret_cast<__half2*>(f0h) + (size_t)t * 2;
    __half2* p1 = reinterpret_cast<__half2*>(f1h) + (size_t)t * 2;
    p0[0] = a; p0[1] = b;
    p1[0] = c; p1[1] = d;
}

// ================= K1: 3x3x32->3 conv + tanh =================================
// Wave = 64 px (8 pg x 8 px) x 8 ch-chunks. Block = 4 waves = 256 px.
// Weight loads (27 float4/thread) amortized over 64 px/wave (2x r4).
// Enc loads: imm-offset from two bases (offsets >= 4096B use base+1024 floats).
__device__ __forceinline__ void fma12(float acc[3], const float wf[12],
                                      float4 x)
{
    float xv[4] = {x.x, x.y, x.z, x.w};
#pragma unroll
    for (int k = 0; k < 4; ++k) {
        acc[0] = fmaf(xv[k], wf[k * 3 + 0], acc[0]);
        acc[1] = fmaf(xv[k], wf[k * 3 + 1], acc[1]);
        acc[2] = fmaf(xv[k], wf[k * 3 + 2], acc[2]);
    }
}

__global__ __launch_bounds__(256, 4) void conv_tanh_kernel(
    const float* __restrict__ enc, const float* __restrict__ cw,
    const float* __restrict__ cb, float* __restrict__ flow,
    float* __restrict__ mask)
{
    int bid = blockIdx.x;                                 // 8192 blocks
    int wb  = (bid & 7) * (NPIX / 256 / 8) + (bid >> 3);  // image n -> XCD n
    int px0 = wb * 256;
    int n = px0 >> 18;
    int h = (px0 >> 9) & (HH - 1);

    int tid  = threadIdx.x;
    int wv   = tid >> 6;
    int lane = tid & 63;
    int p3   = lane >> 3;                                 // pixel in group
    int c4   = lane & 7;                                  // channel chunk

    int wbase = (px0 & (WW - 1)) + wv * 64;               // wave's 64-px seg

    const float4* cwB = reinterpret_cast<const float4*>(cw) + c4 * 3;
    const float* imgbase = enc + ((size_t)n * HH) * (WW * 32);

    float acc[8][3];
#pragma unroll
    for (int pg = 0; pg < 8; ++pg)
        acc[pg][0] = acc[pg][1] = acc[pg][2] = 0.0f;

    bool edge = (wbase == 0) || (wbase == WW - 64);       // wave-uniform

    if (!edge) {
#pragma unroll
        for (int kh = 0; kh < 3; ++kh) {
            int hr = h + kh - 1;
            if ((unsigned)hr >= (unsigned)HH) continue;   // block-uniform
            const float* pB = imgbase + (size_t)hr * (WW * 32)
                            + (wbase - 1 + p3) * 32 + c4 * 4;
            const float* pB2 = pB + 1024;                 // +4096B
#pragma unroll
            for (int kw = 0; kw < 3; ++kw) {
                int t = kh * 3 + kw;
                float wf[12];
                *reinterpret_cast<float4*>(&wf[0]) = cwB[t * 24 + 0];
                *reinterpret_cast<float4*>(&wf[4]) = cwB[t * 24 + 1];
                *reinterpret_cast<float4*>(&wf[8]) = cwB[t * 24 + 2];
#pragma unroll
                for (int pg = 0; pg < 4; ++pg) {
                    float4 x = *reinterpret_cast<const float4*>(
                                   pB + (pg * 8 + kw) * 32);
                    fma12(acc[pg], wf, x);
                }
#pragma unroll
                for (int pg = 4; pg < 8; ++pg) {
                    float4 x = *reinterpret_cast<const float4*>(
                                   pB2 + ((pg - 4) * 8 + kw) * 32);
                    fma12(acc[pg], wf, x);
                }
            }
        }
    } else {
#pragma unroll
        for (int kh = 0; kh < 3; ++kh) {
            int hr = h + kh - 1;
            if ((unsigned)hr >= (unsigned)HH) continue;
            const float* rowp = imgbase + (size_t)hr * (WW * 32);
#pragma unroll
            for (int kw = 0; kw < 3; ++kw) {
                int t = kh * 3 + kw;
                float wf[12];
                *reinterpret_cast<float4*>(&wf[0]) = cwB[t * 24 + 0];
                *reinterpret_cast<float4*>(&wf[4]) = cwB[t * 24 + 1];
                *reinterpret_cast<float4*>(&wf[8]) = cwB[t * 24 + 2];
#pragma unroll
                for (int pg = 0; pg < 8; ++pg) {
                    int wc = wbase + p3 + pg * 8 + kw - 1;
                    float4 x = make_float4(0.f, 0.f, 0.f, 0.f);
                    if ((unsigned)wc < (unsigned)WW)
                        x = *reinterpret_cast<const float4*>(
                                rowp + wc * 32 + c4 * 4);
                    fma12(acc[pg], wf, x);
                }
            }
        }
    }

    float b0 = cb[0], b1 = cb[1], b2 = cb[2];
    size_t rowidx = ((size_t)n * HH + h) * WW;

#pragma unroll
    for (int pg = 0; pg < 8; ++pg) {
        float a0 = acc[pg][0], a1 = acc[pg][1], a2 = acc[pg][2];
#pragma unroll
        for (int off = 1; off < 8; off <<= 1) {           // reduce over c4
            a0 += __shfl_xor(a0, off);
            a1 += __shfl_xor(a1, off);
            a2 += __shfl_xor(a2, off);
        }
        float t0 = tanh_fast(a0 + b0);
        float t1 = tanh_fast(a1 + b1);
        float t2 = tanh_fast(a2 + b2);
        if (c4 == 0) {
            size_t idx = rowidx + (size_t)(wbase + p3 + pg * 8);
            *reinterpret_cast<float2*>(flow + idx * 2) = make_float2(t0, t1);
            mask[idx] = t2;
        }
    }
}

// ================= K2: bilinear warp + blend + TV ===========================
// 4 px/thread: 16 independent pair-gathers in flight per thread (latency-
// bound scatter -> ILP is the lever; r4 at 2px/36VGPR was concurrency-starved)
__device__ __forceinline__ void bilerp_h(const __half* __restrict__ img,
                                         float ch, float cwv, float out[3])
{
    float hp = (ch + 1.0f) * 255.5f;
    float wp = (cwv + 1.0f) * 255.5f;
    int h0 = (int)floorf(hp);
    int w0 = (int)floorf(wp);
    int h1  = min(max(h0 + 1, 0), HH - 1);
    int w1  = min(max(w0 + 1, 0), WW - 1);
    int h0c = min(max(h0, 0), HH - 1);
    int w0c = min(max(w0, 0), WW - 1);
    float wh = (float)h1 - hp;
    float wv = (float)w1 - wp;
    float w_ru = wh * wv;
    float w_rd = (1.0f - wh) * wv;
    float w_lu = wh * (1.0f - wv);
    float w_ld = (1.0f - wh) * (1.0f - wv);

    int q = min(w0c, WW - 2);                 // pair base (pixels q, q+1)
    bool Ahi = (w0c != q);
    bool Bhi = (w1 == q + 1);
    float4 U = *reinterpret_cast<const float4*>(img + (size_t)(((h0c << 9) + q) << 2));
    float4 D = *reinterpret_cast<const float4*>(img + (size_t)(((h1  << 9) + q) << 2));
    float ru_ab = Ahi ? U.z : U.x, ru_c = Ahi ? U.w : U.y;
    float rd_ab = Ahi ? D.z : D.x, rd_c = Ahi ? D.w : D.y;
    float lu_ab = Bhi ? U.z : U.x, lu_c = Bhi ? U.w : U.y;
    float ld_ab = Bhi ? D.z : D.x, ld_c = Bhi ? D.w : D.y;

    float2 ruA = __half22float2(*reinterpret_cast<__half2*>(&ru_ab));
    float2 rdA = __half22float2(*reinterpret_cast<__half2*>(&rd_ab));
    float2 luA = __half22float2(*reinterpret_cast<__half2*>(&lu_ab));
    float2 ldA = __half22float2(*reinterpret_cast<__half2*>(&ld_ab));
    float ruZ = __half2float(reinterpret_cast<__half2*>(&ru_c)->x);
    float rdZ = __half2float(reinterpret_cast<__half2*>(&rd_c)->x);
    float luZ = __half2float(reinterpret_cast<__half2*>(&lu_c)->x);
    float ldZ = __half2float(reinterpret_cast<__half2*>(&ld_c)->x);

    out[0] = w_ru * ruA.x + w_rd * rdA.x + w_lu * luA.x + w_ld * ldA.x;
    out[1] = w_ru * ruA.y + w_rd * rdA.y + w_lu * luA.y + w_ld * ldA.y;
    out[2] = w_ru * ruZ   + w_rd * rdZ   + w_lu * luZ   + w_ld * ldZ;
}

__global__ __launch_bounds__(256, 4) void interp_tv_kernel(
    const __half* __restrict__ f0h, const __half* __restrict__ f1h,
    const float* __restrict__ flow, const float* __restrict__ mask,
    float* __restrict__ stacked, float* __restrict__ tv_out)
{
    int bid = blockIdx.x;                                  // 2048 blocks
    int wb  = (bid & 7) * (NPIX / 1024 / 8) + (bid >> 3);  // image n -> XCD n
    int idx0 = wb * 1024 + (int)threadIdx.x * 4;           // 4 adjacent px
    int w0 = idx0 & (WW - 1);
    int h  = (idx0 >> 9) & (HH - 1);
    int n  = idx0 >> 18;

    float4 fl01 = *reinterpret_cast<const float4*>(flow + (size_t)idx0 * 2);
    float4 fl23 = *reinterpret_cast<const float4*>(flow + (size_t)idx0 * 2 + 4);
    float4 mk   = *reinterpret_cast<const float4*>(mask + idx0);

    float hhv = -1.0f + (float)h * (2.0f / 511.0f);
    float wvx[4];
#pragma unroll
    for (int p = 0; p < 4; ++p)
        wvx[p] = -1.0f + (float)(w0 + p) * (2.0f / 511.0f);

    const __half* i0 = f0h + (size_t)n * (HH * WW * 4);
    const __half* i1 = f1h + (size_t)n * (HH * WW * 4);

    float flp[4][2] = {{fl01.x, fl01.y}, {fl01.z, fl01.w},
                       {fl23.x, fl23.y}, {fl23.z, fl23.w}};
    float o0[4][3], o1[4][3];
#pragma unroll
    for (int p = 0; p < 4; ++p) {
        bilerp_h(i0, hhv + flp[p][0] * 0.5f, wvx[p] + flp[p][1] * 0.5f, o0[p]);
        bilerp_h(i1, hhv - flp[p][0] * 0.5f, wvx[p] - flp[p][1] * 0.5f, o1[p]);
    }

    float mkp[4] = {mk.x, mk.y, mk.z, mk.w};
    float res[12];
#pragma unroll
    for (int p = 0; p < 4; ++p) {
        float m = 0.5f * (1.0f + mkp[p]), om = 1.0f - m;
#pragma unroll
        for (int c = 0; c < 3; ++c)
            res[p * 3 + c] = m * o0[p][c] + om * o1[p][c];
    }
    float4* sp = reinterpret_cast<float4*>(stacked + (size_t)idx0 * 3);
    sp[0] = make_float4(res[0], res[1], res[2], res[3]);
    sp[1] = make_float4(res[4], res[5], res[6], res[7]);
    sp[2] = make_float4(res[8], res[9], res[10], res[11]);

    // ---- TV ----
    float tvf = fabsf(fl01.z - fl01.x) + fabsf(fl01.w - fl01.y)
              + fabsf(fl23.x - fl01.z) + fabsf(fl23.y - fl01.w)
              + fabsf(fl23.z - fl23.x) + fabsf(fl23.w - fl23.y);
    float tvm = fabsf(mk.y - mk.x) + fabsf(mk.z - mk.y) + fabsf(mk.w - mk.z);
    if (h < HH - 1) {
        float4 fd01 = *reinterpret_cast<const float4*>(flow + (size_t)(idx0 + WW) * 2);
        float4 fd23 = *reinterpret_cast<const float4*>(flow + (size_t)(idx0 + WW) * 2 + 4);
        float4 mkd  = *reinterpret_cast<const float4*>(mask + (idx0 + WW));
        tvf += fabsf(fd01.x - fl01.x) + fabsf(fd01.y - fl01.y)
             + fabsf(fd01.z - fl01.z) + fabsf(fd01.w - fl01.w)
             + fabsf(fd23.x - fl23.x) + fabsf(fd23.y - fl23.y)
             + fabsf(fd23.z - fl23.z) + fabsf(fd23.w - fl23.w);
        tvm += fabsf(mkd.x - mk.x) + fabsf(mkd.y - mk.y)
             + fabsf(mkd.z - mk.z) + fabsf(mkd.w - mk.w);
    }
    if (w0 < WW - 4) {
        float2 flr = *reinterpret_cast<const float2*>(flow + (size_t)(idx0 + 4) * 2);
        float  mkr = mask[idx0 + 4];
        tvf += fabsf(flr.x - fl23.z) + fabsf(flr.y - fl23.w);
        tvm += fabsf(mkr - mk.w);
    }
    float tv = GAMMA_FLOW * tvf + GAMMA_MASK * tvm;
#pragma unroll
    for (int off = 32; off > 0; off >>= 1) tv += __shfl_xor(tv, off);
    if ((threadIdx.x & 63) == 0) atomicAdd(tv_out, tv * INV_TOTAL);
}

extern "C" void kernel_launch(void* const* d_in, const int* in_sizes, int n_in,
                              void* d_out, int out_size, void* d_ws, size_t ws_size,
                              hipStream_t stream)
{
    const float* frames  = (const float*)d_in[0];
    const float* encoded = (const float*)d_in[1];
    const float* conv_w  = (const float*)d_in[2];
    const float* conv_b  = (const float*)d_in[3];

    float* out     = (float*)d_out;
    float* stacked = out;                       // NPIX*3
    float* flow    = out + (size_t)NPIX * 3;    // NPIX*2
    float* tv      = out + (size_t)NPIX * 5;    // 1

    hipMemsetAsync(tv, 0, sizeof(float), stream);

    const size_t frame_bytes = (size_t)NPIX * 4 * sizeof(__half); // 16 MiB each
    __half* f0h = (__half*)d_ws;
    __half* f1h = (__half*)((char*)d_ws + frame_bytes);
    float*  mask = (float*)((char*)d_ws + 2 * frame_bytes);

    cvt_kernel<<<NPIX / 256, 256, 0, stream>>>(frames, f0h, f1h);
    conv_tanh_kernel<<<NPIX / 256, 256, 0, stream>>>(encoded, conv_w, conv_b,
                                                     flow, mask);
    interp_tv_kernel<<<NPIX / 1024, 256, 0, stream>>>(
        f0h, f1h, flow, mask, stacked, tv);
}

// Round 6
// 262.137 us; speedup vs baseline: 2.2517x; 2.2517x over previous
//
#include <hip/hip_runtime.h>
#include <hip/hip_fp16.h>
#include <math.h>

#define HH 512
#define WW 512
#define NIMG 8
#define NPIX (NIMG * HH * WW)          // 2,097,152
#define GAMMA_FLOW 0.001f
#define GAMMA_MASK 0.0005f
#define INV_TOTAL (1.0f / (float)(NPIX * 3))

__device__ __forceinline__ float tanh_fast(float x)
{
    float e = __expf(2.0f * x);
    return 1.0f - 2.0f / (e + 1.0f);
}

// ================= K0: frames fp32 NHWC(6) -> two planar fp16 (padded 4/px) ==
__global__ __launch_bounds__(256) void cvt_kernel(
    const float* __restrict__ frames,
    __half* __restrict__ f0h, __half* __restrict__ f1h)
{
    int t = blockIdx.x * 256 + threadIdx.x;            // one pixel
    const float2* fp = reinterpret_cast<const float2*>(frames + (size_t)t * 6);
    float2 v0 = fp[0], v1 = fp[1], v2 = fp[2];
    __half2 a = __floats2half2_rn(v0.x, v0.y);         // f0 ch0,ch1
    __half2 b = __floats2half2_rn(v1.x, 0.0f);         // f0 ch2, pad
    __half2 c = __floats2half2_rn(v1.y, v2.x);         // f1 ch0,ch1
    __half2 d = __floats2half2_rn(v2.y, 0.0f);         // f1 ch2, pad
    __half2* p0 = reinterpret_cast<__half2*>(f0h) + (size_t)t * 2;
    __half2* p1 = reinterpret_cast<__half2*>(f1h) + (size_t)t * 2;
    p0[0] = a; p0[1] = b;
    p1[0] = c; p1[1] = d;
}

// ================= K1: 3x3x32->3 conv + tanh =================================
// EXACT r4 structure (known good ~150us). pg=8 (r5) spilled: acc[8][3] +
// hoisted loads blew the 128-VGPR cap -> 847MB scratch writes. Keep pg=4.
__device__ __forceinline__ void fma12(float acc[3], const float wf[12],
                                      float4 x)
{
    float xv[4] = {x.x, x.y, x.z, x.w};
#pragma unroll
    for (int k = 0; k < 4; ++k) {
        acc[0] = fmaf(xv[k], wf[k * 3 + 0], acc[0]);
        acc[1] = fmaf(xv[k], wf[k * 3 + 1], acc[1]);
        acc[2] = fmaf(xv[k], wf[k * 3 + 2], acc[2]);
    }
}

__global__ __launch_bounds__(256, 4) void conv_tanh_kernel(
    const float* __restrict__ enc, const float* __restrict__ cw,
    const float* __restrict__ cb, float* __restrict__ flow,
    float* __restrict__ mask)
{
    int bid = blockIdx.x;                                 // 16384 blocks
    int wb  = (bid & 7) * (NPIX / 128 / 8) + (bid >> 3);  // image n -> XCD n
    int px0 = wb * 128;
    int n = px0 >> 18;
    int h = (px0 >> 9) & (HH - 1);

    int tid  = threadIdx.x;
    int wv   = tid >> 6;
    int lane = tid & 63;
    int p3   = lane >> 3;                                 // pixel in group
    int c4   = lane & 7;                                  // channel chunk

    int wbase = (px0 & (WW - 1)) + wv * 32;               // wave's 32-px seg

    const float4* cwB = reinterpret_cast<const float4*>(cw) + c4 * 3;
    const float* imgbase = enc + ((size_t)n * HH) * (WW * 32);

    float acc[4][3];
#pragma unroll
    for (int pg = 0; pg < 4; ++pg)
        acc[pg][0] = acc[pg][1] = acc[pg][2] = 0.0f;

    bool edge = (wbase == 0) || (wbase == WW - 32);       // wave-uniform

    if (!edge) {
#pragma unroll
        for (int kh = 0; kh < 3; ++kh) {
            int hr = h + kh - 1;
            if ((unsigned)hr >= (unsigned)HH) continue;   // block-uniform
            const float* pB = imgbase + (size_t)hr * (WW * 32)
                            + (wbase - 1 + p3) * 32 + c4 * 4;
#pragma unroll
            for (int kw = 0; kw < 3; ++kw) {
                int t = kh * 3 + kw;
                float wf[12];
                *reinterpret_cast<float4*>(&wf[0]) = cwB[t * 24 + 0];
                *reinterpret_cast<float4*>(&wf[4]) = cwB[t * 24 + 1];
                *reinterpret_cast<float4*>(&wf[8]) = cwB[t * 24 + 2];
#pragma unroll
                for (int pg = 0; pg < 4; ++pg) {
                    float4 x = *reinterpret_cast<const float4*>(
                                   pB + (pg * 8 + kw) * 32);
                    fma12(acc[pg], wf, x);
                }
            }
        }
    } else {
#pragma unroll
        for (int kh = 0; kh < 3; ++kh) {
            int hr = h + kh - 1;
            if ((unsigned)hr >= (unsigned)HH) continue;
            const float* rowp = imgbase + (size_t)hr * (WW * 32);
#pragma unroll
            for (int kw = 0; kw < 3; ++kw) {
                int t = kh * 3 + kw;
                float wf[12];
                *reinterpret_cast<float4*>(&wf[0]) = cwB[t * 24 + 0];
                *reinterpret_cast<float4*>(&wf[4]) = cwB[t * 24 + 1];
                *reinterpret_cast<float4*>(&wf[8]) = cwB[t * 24 + 2];
#pragma unroll
                for (int pg = 0; pg < 4; ++pg) {
                    int wc = wbase + p3 + pg * 8 + kw - 1;
                    float4 x = make_float4(0.f, 0.f, 0.f, 0.f);
                    if ((unsigned)wc < (unsigned)WW)
                        x = *reinterpret_cast<const float4*>(
                                rowp + wc * 32 + c4 * 4);
                    fma12(acc[pg], wf, x);
                }
            }
        }
    }

    float b0 = cb[0], b1 = cb[1], b2 = cb[2];
    size_t rowidx = ((size_t)n * HH + h) * WW;

#pragma unroll
    for (int pg = 0; pg < 4; ++pg) {
        float a0 = acc[pg][0], a1 = acc[pg][1], a2 = acc[pg][2];
#pragma unroll
        for (int off = 1; off < 8; off <<= 1) {           // reduce over c4
            a0 += __shfl_xor(a0, off);
            a1 += __shfl_xor(a1, off);
            a2 += __shfl_xor(a2, off);
        }
        float t0 = tanh_fast(a0 + b0);
        float t1 = tanh_fast(a1 + b1);
        float t2 = tanh_fast(a2 + b2);
        if (c4 == 0) {
            size_t idx = rowidx + (size_t)(wbase + p3 + pg * 8);
            *reinterpret_cast<float2*>(flow + idx * 2) = make_float2(t0, t1);
            mask[idx] = t2;
        }
    }
}

// ================= K2: bilinear warp + blend + TV ===========================
// 8 px/thread: 32 independent pair-gathers in flight (ILP scaling law held
// r1->r5: dur ~ 1/outstanding-gathers). Cap 128 VGPR via (256,4).
__device__ __forceinline__ void bilerp_h(const __half* __restrict__ img,
                                         float ch, float cwv, float out[3])
{
    float hp = (ch + 1.0f) * 255.5f;
    float wp = (cwv + 1.0f) * 255.5f;
    int h0 = (int)floorf(hp);
    int w0 = (int)floorf(wp);
    int h1  = min(max(h0 + 1, 0), HH - 1);
    int w1  = min(max(w0 + 1, 0), WW - 1);
    int h0c = min(max(h0, 0), HH - 1);
    int w0c = min(max(w0, 0), WW - 1);
    float wh = (float)h1 - hp;
    float wv = (float)w1 - wp;
    float w_ru = wh * wv;
    float w_rd = (1.0f - wh) * wv;
    float w_lu = wh * (1.0f - wv);
    float w_ld = (1.0f - wh) * (1.0f - wv);

    int q = min(w0c, WW - 2);                 // pair base (pixels q, q+1)
    bool Ahi = (w0c != q);
    bool Bhi = (w1 == q + 1);
    float4 U = *reinterpret_cast<const float4*>(img + (size_t)(((h0c << 9) + q) << 2));
    float4 D = *reinterpret_cast<const float4*>(img + (size_t)(((h1  << 9) + q) << 2));
    float ru_ab = Ahi ? U.z : U.x, ru_c = Ahi ? U.w : U.y;
    float rd_ab = Ahi ? D.z : D.x, rd_c = Ahi ? D.w : D.y;
    float lu_ab = Bhi ? U.z : U.x, lu_c = Bhi ? U.w : U.y;
    float ld_ab = Bhi ? D.z : D.x, ld_c = Bhi ? D.w : D.y;

    float2 ruA = __half22float2(*reinterpret_cast<__half2*>(&ru_ab));
    float2 rdA = __half22float2(*reinterpret_cast<__half2*>(&rd_ab));
    float2 luA = __half22float2(*reinterpret_cast<__half2*>(&lu_ab));
    float2 ldA = __half22float2(*reinterpret_cast<__half2*>(&ld_ab));
    float ruZ = __half2float(reinterpret_cast<__half2*>(&ru_c)->x);
    float rdZ = __half2float(reinterpret_cast<__half2*>(&rd_c)->x);
    float luZ = __half2float(reinterpret_cast<__half2*>(&lu_c)->x);
    float ldZ = __half2float(reinterpret_cast<__half2*>(&ld_c)->x);

    out[0] = w_ru * ruA.x + w_rd * rdA.x + w_lu * luA.x + w_ld * ldA.x;
    out[1] = w_ru * ruA.y + w_rd * rdA.y + w_lu * luA.y + w_ld * ldA.y;
    out[2] = w_ru * ruZ   + w_rd * rdZ   + w_lu * luZ   + w_ld * ldZ;
}

__global__ __launch_bounds__(256, 4) void interp_tv_kernel(
    const __half* __restrict__ f0h, const __half* __restrict__ f1h,
    const float* __restrict__ flow, const float* __restrict__ mask,
    float* __restrict__ stacked, float* __restrict__ tv_out)
{
    int bid = blockIdx.x;                                  // 1024 blocks
    int wb  = (bid & 7) * (NPIX / 2048 / 8) + (bid >> 3);  // image n -> XCD n
    int idx0 = wb * 2048 + (int)threadIdx.x * 8;           // 8 adjacent px
    int w0 = idx0 & (WW - 1);
    int h  = (idx0 >> 9) & (HH - 1);
    int n  = idx0 >> 18;

    float4 fl[4];                                          // flow, 8 px
#pragma unroll
    for (int j = 0; j < 4; ++j)
        fl[j] = *reinterpret_cast<const float4*>(flow + (size_t)idx0 * 2 + j * 4);
    float4 mkA = *reinterpret_cast<const float4*>(mask + idx0);
    float4 mkB = *reinterpret_cast<const float4*>(mask + idx0 + 4);
    const float* flp = reinterpret_cast<const float*>(fl);
    float mkp[8] = {mkA.x, mkA.y, mkA.z, mkA.w, mkB.x, mkB.y, mkB.z, mkB.w};

    float hhv = -1.0f + (float)h * (2.0f / 511.0f);

    const __half* i0 = f0h + (size_t)n * (HH * WW * 4);
    const __half* i1 = f1h + (size_t)n * (HH * WW * 4);

    float res[24];
#pragma unroll
    for (int p = 0; p < 8; ++p) {
        float wvx = -1.0f + (float)(w0 + p) * (2.0f / 511.0f);
        float fx = flp[p * 2], fy = flp[p * 2 + 1];
        float o0[3], o1[3];
        bilerp_h(i0, hhv + fx * 0.5f, wvx + fy * 0.5f, o0);
        bilerp_h(i1, hhv - fx * 0.5f, wvx - fy * 0.5f, o1);
        float m = 0.5f * (1.0f + mkp[p]), om = 1.0f - m;
#pragma unroll
        for (int c = 0; c < 3; ++c)
            res[p * 3 + c] = m * o0[c] + om * o1[c];
    }
    float4* sp = reinterpret_cast<float4*>(stacked + (size_t)idx0 * 3);
#pragma unroll
    for (int j = 0; j < 6; ++j)
        sp[j] = make_float4(res[j * 4], res[j * 4 + 1],
                            res[j * 4 + 2], res[j * 4 + 3]);

    // ---- TV ----
    float tvf = 0.0f, tvm = 0.0f;
#pragma unroll
    for (int p = 0; p < 7; ++p) {                          // in-register right
        tvf += fabsf(flp[p * 2 + 2] - flp[p * 2])
             + fabsf(flp[p * 2 + 3] - flp[p * 2 + 1]);
        tvm += fabsf(mkp[p + 1] - mkp[p]);
    }
    if (w0 < WW - 8) {                                     // seam right
        float2 flr = *reinterpret_cast<const float2*>(flow + (size_t)(idx0 + 8) * 2);
        float  mkr = mask[idx0 + 8];
        tvf += fabsf(flr.x - flp[14]) + fabsf(flr.y - flp[15]);
        tvm += fabsf(mkr - mkp[7]);
    }
    if (h < HH - 1) {                                      // down row
#pragma unroll
        for (int j = 0; j < 4; ++j) {
            float4 fd = *reinterpret_cast<const float4*>(
                            flow + (size_t)(idx0 + WW) * 2 + j * 4);
            tvf += fabsf(fd.x - flp[j * 4 + 0]) + fabsf(fd.y - flp[j * 4 + 1])
                 + fabsf(fd.z - flp[j * 4 + 2]) + fabsf(fd.w - flp[j * 4 + 3]);
        }
        float4 mdA = *reinterpret_cast<const float4*>(mask + idx0 + WW);
        float4 mdB = *reinterpret_cast<const float4*>(mask + idx0 + WW + 4);
        tvm += fabsf(mdA.x - mkp[0]) + fabsf(mdA.y - mkp[1])
             + fabsf(mdA.z - mkp[2]) + fabsf(mdA.w - mkp[3])
             + fabsf(mdB.x - mkp[4]) + fabsf(mdB.y - mkp[5])
             + fabsf(mdB.z - mkp[6]) + fabsf(mdB.w - mkp[7]);
    }
    float tv = GAMMA_FLOW * tvf + GAMMA_MASK * tvm;
#pragma unroll
    for (int off = 32; off > 0; off >>= 1) tv += __shfl_xor(tv, off);
    if ((threadIdx.x & 63) == 0) atomicAdd(tv_out, tv * INV_TOTAL);
}

extern "C" void kernel_launch(void* const* d_in, const int* in_sizes, int n_in,
                              void* d_out, int out_size, void* d_ws, size_t ws_size,
                              hipStream_t stream)
{
    const float* frames  = (const float*)d_in[0];
    const float* encoded = (const float*)d_in[1];
    const float* conv_w  = (const float*)d_in[2];
    const float* conv_b  = (const float*)d_in[3];

    float* out     = (float*)d_out;
    float* stacked = out;                       // NPIX*3
    float* flow    = out + (size_t)NPIX * 3;    // NPIX*2
    float* tv      = out + (size_t)NPIX * 5;    // 1

    hipMemsetAsync(tv, 0, sizeof(float), stream);

    const size_t frame_bytes = (size_t)NPIX * 4 * sizeof(__half); // 16 MiB each
    __half* f0h = (__half*)d_ws;
    __half* f1h = (__half*)((char*)d_ws + frame_bytes);
    float*  mask = (float*)((char*)d_ws + 2 * frame_bytes);

    cvt_kernel<<<NPIX / 256, 256, 0, stream>>>(frames, f0h, f1h);
    conv_tanh_kernel<<<NPIX / 128, 256, 0, stream>>>(encoded, conv_w, conv_b,
                                                     flow, mask);
    interp_tv_kernel<<<NPIX / 2048, 256, 0, stream>>>(
        f0h, f1h, flow, mask, stacked, tv);
}